// Round 1
// baseline (3977.148 us; speedup 1.0000x reference)
//
#include <hip/hip_runtime.h>

#define LL 256
#define BB 128
#define DD 256
#define HH 256

typedef float  floatx4 __attribute__((ext_vector_type(4)));
typedef short  short8  __attribute__((ext_vector_type(8)));

struct Params {
  const float* inputs;
  const float* ioux_w[2]; const float* ioux_b[2];
  const float* iouh_w[2]; const float* iouh_b[2];
  const float* fx_w[2];   const float* fx_b[2];
  const float* fh_w[2];   const float* fh_b[2];
};

__device__ __forceinline__ unsigned short f2bf(float f) {
  unsigned u = __float_as_uint(f);
  u += 0x7fffu + ((u >> 16) & 1u);
  return (unsigned short)(u >> 16);
}
__device__ __forceinline__ float bf2f(unsigned u) { return __uint_as_float(u << 16); }
__device__ __forceinline__ float sigm(float x) { return 1.0f / (1.0f + __expf(-x)); }
__device__ __forceinline__ float tanh_(float x) { return 1.0f - 2.0f / (1.0f + __expf(2.0f * x)); }

// ---------------------------------------------------------------------------
// init: zero accumulators, bf16-convert inputs & x-weights (interleaved col
// order cc = j*4+gate), build fp32 Wpack[d][k][j][4] and bias4[d][j][4].
// ---------------------------------------------------------------------------
__global__ __launch_bounds__(256) void init_kernel(Params p, float* acc_c,
    unsigned short* a16, unsigned short* w16, float* wpack, float* bias4) {
  size_t tid = (size_t)blockIdx.x * blockDim.x + threadIdx.x;
  size_t nth = (size_t)gridDim.x * blockDim.x;

  // zero acc_c and acc_h (contiguous): 2 * 128*257*256 floats = 4,210,688 float4
  float4 z; z.x = z.y = z.z = z.w = 0.f;
  float4* az = (float4*)acc_c;
  for (size_t i = tid; i < 4210688u; i += nth) az[i] = z;

  // inputs -> bf16 (8,388,608 elems = 2,097,152 float4)
  const float4* in4 = (const float4*)p.inputs;
  for (size_t i = tid; i < 2097152u; i += nth) {
    float4 v = in4[i];
    ((ushort4*)a16)[i] = make_ushort4(f2bf(v.x), f2bf(v.y), f2bf(v.z), f2bf(v.w));
  }

  // w16[d][cc][k], cc = j*4+g : g<3 -> ioux_w row g*256+j ; g==3 -> fx_w row j
  for (size_t i = tid; i < 524288u; i += nth) {
    int d = (int)(i >> 18); int r = (int)(i & 262143);
    int cc = r >> 8; int k = r & 255;
    int j = cc >> 2; int g = cc & 3;
    float s = (g < 3) ? p.ioux_w[d][(g * 256 + j) * 256 + k]
                      : p.fx_w[d][j * 256 + k];
    w16[i] = f2bf(s);
  }

  // wpack[d][k][j][4] fp32 : g<3 -> iouh_w[g*256+j][k] ; g==3 -> fh_w[j][k]
  for (size_t i = tid; i < 524288u; i += nth) {
    int d = (int)(i >> 18); int r = (int)(i & 262143);
    int k = r >> 10; int j = (r >> 2) & 255; int g = r & 3;
    float s = (g < 3) ? p.iouh_w[d][(g * 256 + j) * 256 + k]
                      : p.fh_w[d][j * 256 + k];
    wpack[i] = s;
  }

  // bias4[d][j][4] = x-bias + h-bias (folded once)
  for (size_t i = tid; i < 2048u; i += nth) {
    int d = (int)(i >> 10); int r = (int)(i & 1023);
    int j = r >> 2; int g = r & 3;
    bias4[i] = (g < 3) ? (p.ioux_b[d][g * 256 + j] + p.iouh_b[d][g * 256 + j])
                       : (p.fx_b[d][j] + p.fh_b[d][j]);
  }
}

// ---------------------------------------------------------------------------
// x-projection GEMM: xproj[d][m=(n,b)][cc] = sum_k A16[m][k] * W16[d][cc][k]
// bf16 MFMA 16x16x32, one wave per 16x16 tile, bf16 output.
// ---------------------------------------------------------------------------
__global__ __launch_bounds__(256) void xproj_gemm(
    const unsigned short* __restrict__ a16,
    const unsigned short* __restrict__ w16,
    unsigned short* __restrict__ xproj) {
  int lane = threadIdx.x & 63;
  int wv   = threadIdx.x >> 6;
  int m0   = blockIdx.x * 16;
  int n0   = (blockIdx.y * 4 + wv) * 16;
  int d    = blockIdx.z;
  int quad = lane >> 4;
  int l16  = lane & 15;
  const unsigned short* Ar = a16 + (size_t)(m0 + l16) * 256 + quad * 8;
  const unsigned short* Br = w16 + (size_t)d * 262144u + (size_t)(n0 + l16) * 256 + quad * 8;
  floatx4 acc = {0.f, 0.f, 0.f, 0.f};
#pragma unroll
  for (int kk = 0; kk < 8; ++kk) {
    short8 a = *(const short8*)(Ar + kk * 32);
    short8 b = *(const short8*)(Br + kk * 32);
    acc = __builtin_amdgcn_mfma_f32_16x16x32_bf16(a, b, acc, 0, 0, 0);
  }
  unsigned short* out = xproj + (size_t)d * 33554432u;
  int col = n0 + l16;
#pragma unroll
  for (int r = 0; r < 4; ++r) {
    int row = m0 + quad * 4 + r;
    out[(size_t)row * 1024 + col] = f2bf(acc[r]);
  }
}

// ---------------------------------------------------------------------------
// one recurrence step (both directions). grid (cs=32, bg=8, dir=2), block 128.
// thread = (g = tid>>3 in [0,16), j0 = tid&7); owns cell (b = bg*16+g, col j).
// dt: node idx = indexes[t]; gather child-sums from acc, scatter c,h to parent.
// td: node idx = indexes[255-t] (= t); gather parent state from d_out.
// ---------------------------------------------------------------------------
__global__ __launch_bounds__(128) void step_kernel(int t,
    const float* __restrict__ wpack, const float* __restrict__ bias4,
    const unsigned short* __restrict__ xproj,
    float* __restrict__ acc_c, float* __restrict__ acc_h,
    float* __restrict__ cells, float* __restrict__ hidd,
    const int* __restrict__ indexes, const int* __restrict__ parents) {
  __shared__ float4 WsV[2048];      // [k=256][j0=8] fp32x4 (i,o,u,f)  32 KB
  __shared__ float  shF[16 * 260];  // 16 batch rows, padded stride 260  16.6 KB

  int tid = threadIdx.x;
  int cs = blockIdx.x, bg = blockIdx.y, d = blockIdx.z;
  int idx = (d == 0) ? indexes[t * BB] : indexes[(255 - t) * BB];

  // stage recurrent-weight slice (cols cs*8 .. cs*8+7)
  const float4* wp4 = (const float4*)wpack + (size_t)d * 65536u;
  for (int v = tid; v < 2048; v += 128) {
    int k = v >> 3, jj = v & 7;
    WsV[v] = wp4[k * 256 + cs * 8 + jj];
  }
  // stage sum_h (dt) / parent h (td) for 16 batch rows
  float4* shV = (float4*)shF;  // row stride = 65 float4 (=260 floats)
  for (int v = tid; v < 1024; v += 128) {
    int g = v >> 6, k4 = v & 63;
    int b = bg * 16 + g;
    float4 val;
    if (d == 0) {
      val = *(const float4*)(acc_h + ((size_t)b * 257 + idx) * 256 + k4 * 4);
    } else {
      int par = parents[idx * BB + b];
      if (par == LL) { val.x = val.y = val.z = val.w = 0.f; }
      else val = *(const float4*)(hidd + ((size_t)par * BB + b) * 512 + 256 + k4 * 4);
    }
    shV[g * 65 + k4] = val;
  }

  int g = tid >> 3, j0 = tid & 7;
  int j = cs * 8 + j0;
  int b = bg * 16 + g;
  int par = parents[idx * BB + b];
  float sc;
  if (d == 0) sc = acc_c[((size_t)b * 257 + idx) * 256 + j];
  else        sc = (par == LL) ? 0.f
                   : cells[((size_t)par * BB + b) * 512 + 256 + j];
  __syncthreads();

  float4 acc = ((const float4*)bias4)[d * 256 + j];
  const float* shRow = shF + g * 260;
#pragma unroll 8
  for (int k = 0; k < 256; ++k) {
    float4 w = WsV[k * 8 + j0];
    float s = shRow[k];
    acc.x = fmaf(s, w.x, acc.x);
    acc.y = fmaf(s, w.y, acc.y);
    acc.z = fmaf(s, w.z, acc.z);
    acc.w = fmaf(s, w.w, acc.w);
  }

  // add x-projection (bf16), gate, write out
  uint2 xv = *(const uint2*)(xproj +
      (((size_t)d * 32768u + (size_t)idx * BB + b) * 1024 + j * 4));
  float pi = acc.x + bf2f(xv.x & 0xffffu);
  float po = acc.y + bf2f(xv.x >> 16);
  float pu = acc.z + bf2f(xv.y & 0xffffu);
  float pf = acc.w + bf2f(xv.y >> 16);
  float gi = sigm(pi), go = sigm(po), gu = tanh_(pu), gf = sigm(pf);
  float c = gi * gu + gf * sc;
  float h = go * tanh_(c);
  size_t ob = ((size_t)idx * BB + b) * 512;
  if (d == 0) {
    cells[ob + j] = c;
    hidd[ob + j]  = h;
    size_t ai = ((size_t)b * 257 + par) * 256 + j;  // exclusive (b,j) owner: no atomics
    acc_c[ai] += c;
    acc_h[ai] += h;
  } else {
    cells[ob + 256 + j] = c;
    hidd[ob + 256 + j]  = h;
  }
}

// ---------------------------------------------------------------------------
extern "C" void kernel_launch(void* const* d_in, const int* in_sizes, int n_in,
                              void* d_out, int out_size, void* d_ws, size_t ws_size,
                              hipStream_t stream) {
  Params p;
  p.inputs = (const float*)d_in[0];
  const int* indexes = (const int*)d_in[1];
  const int* parents = (const int*)d_in[2];
  for (int d = 0; d < 2; ++d) {
    int o = 3 + d * 8;
    p.ioux_w[d] = (const float*)d_in[o + 0];
    p.ioux_b[d] = (const float*)d_in[o + 1];
    p.iouh_w[d] = (const float*)d_in[o + 2];
    p.iouh_b[d] = (const float*)d_in[o + 3];
    p.fx_w[d]   = (const float*)d_in[o + 4];
    p.fx_b[d]   = (const float*)d_in[o + 5];
    p.fh_w[d]   = (const float*)d_in[o + 6];
    p.fh_b[d]   = (const float*)d_in[o + 7];
  }

  // workspace carve (221,519,872 bytes total)
  float* acc_c = (float*)d_ws;                      // [128][257][256] f32
  float* acc_h = acc_c + 8421376u;                  // [128][257][256] f32
  unsigned short* xproj = (unsigned short*)(acc_h + 8421376u);  // [2][32768][1024] bf16
  float* wpack = (float*)(xproj + 67108864u);       // [2][256][256][4] f32
  float* bias4 = wpack + 524288u;                   // [2][256][4] f32
  unsigned short* a16 = (unsigned short*)(bias4 + 2048u);       // [32768][256] bf16
  unsigned short* w16 = a16 + 8388608u;             // [2][1024][256] bf16

  float* cells = (float*)d_out;                     // [256][128][512]
  float* hidd  = cells + 16777216u;                 // [256][128][512]

  init_kernel<<<dim3(1024), dim3(256), 0, stream>>>(p, acc_c, a16, w16, wpack, bias4);
  xproj_gemm<<<dim3(2048, 16, 2), dim3(256), 0, stream>>>(a16, w16, xproj);
  for (int t = 0; t < 256; ++t) {
    step_kernel<<<dim3(32, 8, 2), dim3(128), 0, stream>>>(t, wpack, bias4, xproj,
        acc_c, acc_h, cells, hidd, indexes, parents);
  }
}

// Round 2
// 1951.318 us; speedup vs baseline: 2.0382x; 2.0382x over previous
//
#include <hip/hip_runtime.h>

#define LL 256
#define BB 128
#define NLEV 48

typedef float  floatx4 __attribute__((ext_vector_type(4)));
typedef short  short8  __attribute__((ext_vector_type(8)));

struct Params {
  const float* inputs;
  const float* ioux_w[2]; const float* ioux_b[2];
  const float* iouh_w[2]; const float* iouh_b[2];
  const float* fx_w[2];   const float* fx_b[2];
  const float* fh_w[2];   const float* fh_b[2];
};

__device__ __forceinline__ unsigned short f2bf(float f) {
  unsigned u = __float_as_uint(f);
  u += 0x7fffu + ((u >> 16) & 1u);
  return (unsigned short)(u >> 16);
}
__device__ __forceinline__ float bf2f(unsigned u) { return __uint_as_float(u << 16); }
__device__ __forceinline__ float sigm(float x) { return 1.0f / (1.0f + __expf(-x)); }
__device__ __forceinline__ float tanh_(float x) { return 1.0f - 2.0f / (1.0f + __expf(2.0f * x)); }

// ---------------------------------------------------------------------------
// prep: bf16 inputs, bf16 x-weights (interleaved cc=j*4+g), bf16 h-weights
// (natural rows g*256+j), folded bias4[d][j][4]; zero level counts.
// ---------------------------------------------------------------------------
__global__ __launch_bounds__(256) void prep_kernel(Params p,
    unsigned short* a16, unsigned short* w16x, unsigned short* w16h,
    float* bias4, int* lvcnt) {
  size_t tid = (size_t)blockIdx.x * blockDim.x + threadIdx.x;
  size_t nth = (size_t)gridDim.x * blockDim.x;

  const float4* in4 = (const float4*)p.inputs;
  for (size_t i = tid; i < 2097152u; i += nth) {
    float4 v = in4[i];
    ((ushort4*)a16)[i] = make_ushort4(f2bf(v.x), f2bf(v.y), f2bf(v.z), f2bf(v.w));
  }
  // w16x[d][cc=j*4+g][k]
  for (size_t i = tid; i < 524288u; i += nth) {
    int d = (int)(i >> 18); int r = (int)(i & 262143);
    int cc = r >> 8; int k = r & 255;
    int j = cc >> 2; int g = cc & 3;
    float s = (g < 3) ? p.ioux_w[d][(g * 256 + j) * 256 + k]
                      : p.fx_w[d][j * 256 + k];
    w16x[i] = f2bf(s);
  }
  // w16h[d][row=g*256+j][k]  (natural concat [iouh; fh])
  for (size_t i = tid; i < 524288u; i += nth) {
    int d = (int)(i >> 18); int r = (int)(i & 262143);
    int row = r >> 8; int k = r & 255;
    float s = (row < 768) ? p.iouh_w[d][row * 256 + k]
                          : p.fh_w[d][(row - 768) * 256 + k];
    w16h[i] = f2bf(s);
  }
  for (size_t i = tid; i < 2048u; i += nth) {
    int d = (int)(i >> 10); int r = (int)(i & 1023);
    int j = r >> 2; int g = r & 3;
    bias4[i] = (g < 3) ? (p.ioux_b[d][g * 256 + j] + p.iouh_b[d][g * 256 + j])
                       : (p.fx_b[d][j] + p.fh_b[d][j]);
  }
  for (size_t i = tid; i < 2u * NLEV; i += nth) lvcnt[i] = 0;
}

// ---------------------------------------------------------------------------
// levels: per-b tree walks -> dt heights, td depths; children CSR; histograms.
// grid = 128 WGs (one per batch), 256 threads.
// ---------------------------------------------------------------------------
__global__ __launch_bounds__(256) void levels_kernel(
    const int* __restrict__ parents, int* __restrict__ lev_g,
    int* __restrict__ csr_off, int* __restrict__ csr_dat, int* __restrict__ lvcnt) {
  __shared__ int parL[256], lvdt[256], lvtd[256];
  __shared__ int cmax[257], ccnt[257], coff[257], ccur[257];
  __shared__ int histd[NLEV], histt[NLEV];
  int b = blockIdx.x, t = threadIdx.x;

  parL[t] = parents[t * BB + b];              // node0 -> 256
  for (int v = t; v < 257; v += 256) { cmax[v] = -1; ccnt[v] = 0; }
  if (t < NLEV) { histd[t] = 0; histt[t] = 0; }
  __syncthreads();

  if (t == 0) {                                // td depths
    lvtd[0] = 0;
    for (int i = 1; i < 256; ++i) lvtd[i] = lvtd[parL[i]] + 1;
  }
  if (t == 1) {                                // dt heights
    for (int i = 255; i >= 1; --i) {
      int l = cmax[i] + 1;
      lvdt[i] = l;
      int p = parL[i];
      if (cmax[p] < l) cmax[p] = l;
    }
    lvdt[0] = cmax[0] + 1;
  }
  __syncthreads();

  int l1 = min(lvdt[t], NLEV - 1);
  int l2 = min(lvtd[t], NLEV - 1);
  atomicAdd(&histd[l1], 1);
  atomicAdd(&histt[l2], 1);
  if (t >= 1) atomicAdd(&ccnt[parL[t]], 1);
  lev_g[b * 256 + t] = l1;
  lev_g[32768 + b * 256 + t] = l2;
  __syncthreads();

  if (t == 0) {
    int s = 0;
    for (int i = 0; i < 257; ++i) { coff[i] = s; s += ccnt[i]; }
  }
  __syncthreads();
  for (int v = t; v < 257; v += 256) ccur[v] = coff[v];
  __syncthreads();
  if (t >= 1) {
    int pos = atomicAdd(&ccur[parL[t]], 1);
    csr_dat[b * 256 + pos] = t;
  }
  for (int v = t; v < 257; v += 256) csr_off[b * 260 + v] = coff[v];
  if (t < NLEV) {
    if (histd[t]) atomicAdd(&lvcnt[t], histd[t]);
    if (histt[t]) atomicAdd(&lvcnt[NLEV + t], histt[t]);
  }
}

// ---------------------------------------------------------------------------
// scan: prefix-sum level counts -> offsets + cursors. 1 WG.
// ---------------------------------------------------------------------------
__global__ __launch_bounds__(128) void scan_kernel(const int* __restrict__ lvcnt,
                                                   int* __restrict__ lvoff,
                                                   int* __restrict__ lvcur) {
  __shared__ int c[2 * NLEV], o[2 * (NLEV + 1)];
  int t = threadIdx.x;
  if (t < 2 * NLEV) c[t] = lvcnt[t];
  __syncthreads();
  if (t < 2) {
    int s = 0;
    for (int l = 0; l < NLEV; ++l) { o[t * (NLEV + 1) + l] = s; s += c[t * NLEV + l]; }
    o[t * (NLEV + 1) + NLEV] = s;
  }
  __syncthreads();
  if (t < 2 * (NLEV + 1)) lvoff[t] = o[t];
  if (t < 2 * NLEV) lvcur[t] = o[(t / NLEV) * (NLEV + 1) + (t % NLEV)];
}

// ---------------------------------------------------------------------------
// scatter: counting-sort (b,node) pairs by level. grid (128, 2), 256 thr.
// ---------------------------------------------------------------------------
__global__ __launch_bounds__(256) void scatter_kernel(const int* __restrict__ lev_g,
    int* __restrict__ lvcur, unsigned* __restrict__ plist) {
  __shared__ int hist[NLEV], base[NLEV], cnt2[NLEV];
  int b = blockIdx.x, d = blockIdx.y, t = threadIdx.x;
  if (t < NLEV) { hist[t] = 0; cnt2[t] = 0; }
  __syncthreads();
  int l = lev_g[d * 32768 + b * 256 + t];
  atomicAdd(&hist[l], 1);
  __syncthreads();
  if (t < NLEV && hist[t] > 0) base[t] = atomicAdd(&lvcur[d * NLEV + t], hist[t]);
  __syncthreads();
  int r = atomicAdd(&cnt2[l], 1);
  plist[d * 32768 + base[l] + r] = ((unsigned)b << 16) | (unsigned)t;
}

// ---------------------------------------------------------------------------
// x-projection GEMM: xproj[d][node*128+b][cc=j*4+g] bf16, MFMA 16x16x32.
// ---------------------------------------------------------------------------
__global__ __launch_bounds__(256) void xproj_gemm(
    const unsigned short* __restrict__ a16,
    const unsigned short* __restrict__ w16x,
    unsigned short* __restrict__ xproj) {
  int lane = threadIdx.x & 63;
  int wv   = threadIdx.x >> 6;
  int m0   = blockIdx.x * 16;
  int n0   = (blockIdx.y * 4 + wv) * 16;
  int d    = blockIdx.z;
  int quad = lane >> 4;
  int l16  = lane & 15;
  const unsigned short* Ar = a16 + (size_t)(m0 + l16) * 256 + quad * 8;
  const unsigned short* Br = w16x + (size_t)d * 262144u + (size_t)(n0 + l16) * 256 + quad * 8;
  floatx4 acc = {0.f, 0.f, 0.f, 0.f};
#pragma unroll
  for (int kk = 0; kk < 8; ++kk) {
    short8 a = *(const short8*)(Ar + kk * 32);
    short8 b = *(const short8*)(Br + kk * 32);
    acc = __builtin_amdgcn_mfma_f32_16x16x32_bf16(a, b, acc, 0, 0, 0);
  }
  unsigned short* out = xproj + (size_t)d * 33554432u;
  int col = n0 + l16;
#pragma unroll
  for (int r = 0; r < 4; ++r) {
    int row = m0 + quad * 4 + r;
    out[(size_t)row * 1024 + col] = f2bf(acc[r]);
  }
}

// ---------------------------------------------------------------------------
// level step: process all (b,node) pairs of level l, both directions.
// grid (256, 1, 2), block 256 (4 waves). M-tile = 16 pairs.
//   A-row: dt: sum of children (c,h) gathered fp32; td: parent (c,h).
//   GEMM: bf16 MFMA vs w16h rows (gate-planar), epilogue fused.
// ---------------------------------------------------------------------------
__global__ __launch_bounds__(256) void step_kernel(int l,
    const unsigned short* __restrict__ w16h, const float* __restrict__ bias4,
    const unsigned short* __restrict__ xproj,
    const int* __restrict__ lvoff, const unsigned* __restrict__ plist,
    const int* __restrict__ csr_off, const int* __restrict__ csr_dat,
    const int* __restrict__ parents,
    float* __restrict__ cells, float* __restrict__ hidd) {
  __shared__ unsigned short AhL[16 * 264];   // bf16 A rows (sum_h / parent h)
  __shared__ float ScL[16 * 260];            // fp32 sum_c / parent c
  __shared__ int nL[16], bL[16], vL[16];

  int d = blockIdx.z;
  int i0 = lvoff[d * (NLEV + 1) + l];
  int i1 = lvoff[d * (NLEV + 1) + l + 1];
  int np = i1 - i0;
  if (np <= 0) return;
  int ntiles = (np + 15) >> 4;

  int tid = threadIdx.x;
  int wv = tid >> 6, lane = tid & 63, l16 = lane & 15, quad = lane >> 4;

  for (int tile = blockIdx.x; tile < ntiles; tile += gridDim.x) {
    // ---- stage 16 A rows ----
    int m = tid >> 4, seg = tid & 15;
    int gi = i0 + tile * 16 + m;
    int valid = gi < i1;
    int b = 0, node = 0;
    if (valid) { unsigned pr = plist[d * 32768 + gi]; b = pr >> 16; node = pr & 0xffff; }
    float hs[16], cs[16];
#pragma unroll
    for (int q = 0; q < 16; ++q) { hs[q] = 0.f; cs[q] = 0.f; }
    if (valid) {
      if (d == 0) {
        int o0 = csr_off[b * 260 + node], o1 = csr_off[b * 260 + node + 1];
        for (int e = o0; e < o1; ++e) {
          int cn = csr_dat[b * 256 + e];
          const float4* hp = (const float4*)(hidd + ((size_t)cn * BB + b) * 512) + seg * 4;
          const float4* cp = (const float4*)(cells + ((size_t)cn * BB + b) * 512) + seg * 4;
#pragma unroll
          for (int q = 0; q < 4; ++q) {
            float4 v = hp[q];
            hs[q * 4 + 0] += v.x; hs[q * 4 + 1] += v.y; hs[q * 4 + 2] += v.z; hs[q * 4 + 3] += v.w;
            float4 w = cp[q];
            cs[q * 4 + 0] += w.x; cs[q * 4 + 1] += w.y; cs[q * 4 + 2] += w.z; cs[q * 4 + 3] += w.w;
          }
        }
      } else {
        int par = parents[node * BB + b];
        if (par != LL) {
          const float4* hp = (const float4*)(hidd + ((size_t)par * BB + b) * 512 + 256) + seg * 4;
          const float4* cp = (const float4*)(cells + ((size_t)par * BB + b) * 512 + 256) + seg * 4;
#pragma unroll
          for (int q = 0; q < 4; ++q) {
            float4 v = hp[q];
            hs[q * 4 + 0] = v.x; hs[q * 4 + 1] = v.y; hs[q * 4 + 2] = v.z; hs[q * 4 + 3] = v.w;
            float4 w = cp[q];
            cs[q * 4 + 0] = w.x; cs[q * 4 + 1] = w.y; cs[q * 4 + 2] = w.z; cs[q * 4 + 3] = w.w;
          }
        }
      }
    }
    // pack to LDS
    union { unsigned short u[16]; uint4 q[2]; } pk;
#pragma unroll
    for (int q = 0; q < 16; ++q) pk.u[q] = f2bf(hs[q]);
    *(uint4*)&AhL[m * 264 + seg * 16]     = pk.q[0];
    *(uint4*)&AhL[m * 264 + seg * 16 + 8] = pk.q[1];
#pragma unroll
    for (int q = 0; q < 4; ++q)
      *(float4*)&ScL[m * 260 + seg * 16 + q * 4] =
          make_float4(cs[q * 4 + 0], cs[q * 4 + 1], cs[q * 4 + 2], cs[q * 4 + 3]);
    if (seg == 0) { nL[m] = node; bL[m] = b; vL[m] = valid; }
    __syncthreads();

    // ---- A fragments (shared across all 16 acc groups of this wave) ----
    short8 af[8];
    const unsigned short* Arow = &AhL[l16 * 264 + quad * 8];
#pragma unroll
    for (int kc = 0; kc < 8; ++kc) af[kc] = *(const short8*)(Arow + kc * 32);

    // ---- 4 j-tiles per wave x 4 gates ----
    floatx4 acc[4][4];
    const unsigned short* wbase = w16h + (size_t)d * 262144u;
#pragma unroll
    for (int jt = 0; jt < 4; ++jt) {
      int jtile = wv * 4 + jt;
#pragma unroll
      for (int g = 0; g < 4; ++g) {
        const unsigned short* Bp = wbase + (size_t)((g << 8) + (jtile << 4) + l16) * 256 + quad * 8;
        floatx4 a = {0.f, 0.f, 0.f, 0.f};
#pragma unroll
        for (int kc = 0; kc < 8; ++kc) {
          short8 bf = *(const short8*)(Bp + kc * 32);
          a = __builtin_amdgcn_mfma_f32_16x16x32_bf16(af[kc], bf, a, 0, 0, 0);
        }
        acc[jt][g] = a;
      }
    }

    // ---- epilogue ----
#pragma unroll
    for (int jt = 0; jt < 4; ++jt) {
      int jtile = wv * 4 + jt;
      int j = jtile * 16 + l16;
      float4 bi4 = ((const float4*)bias4)[d * 256 + j];
#pragma unroll
      for (int r = 0; r < 4; ++r) {
        int mm = quad * 4 + r;
        if (!vL[mm]) continue;
        int bb = bL[mm], nn = nL[mm];
        const unsigned short* xp = xproj + ((size_t)d * 32768u + (size_t)nn * BB + bb) * 1024 + j * 4;
        uint2 xv = *(const uint2*)xp;
        float pi = acc[jt][0][r] + bi4.x + bf2f(xv.x & 0xffffu);
        float po = acc[jt][1][r] + bi4.y + bf2f(xv.x >> 16);
        float pu = acc[jt][2][r] + bi4.z + bf2f(xv.y & 0xffffu);
        float pf = acc[jt][3][r] + bi4.w + bf2f(xv.y >> 16);
        float gi = sigm(pi), go = sigm(po), gu = tanh_(pu), gf = sigm(pf);
        float sc = ScL[mm * 260 + j];
        float c = gi * gu + gf * sc;
        float h = go * tanh_(c);
        size_t ob = ((size_t)nn * BB + bb) * 512 + (d << 8) + j;
        cells[ob] = c;
        hidd[ob]  = h;
      }
    }
    __syncthreads();
  }
}

// ---------------------------------------------------------------------------
extern "C" void kernel_launch(void* const* d_in, const int* in_sizes, int n_in,
                              void* d_out, int out_size, void* d_ws, size_t ws_size,
                              hipStream_t stream) {
  Params p;
  p.inputs = (const float*)d_in[0];
  const int* parents = (const int*)d_in[2];
  for (int d = 0; d < 2; ++d) {
    int o = 3 + d * 8;
    p.ioux_w[d] = (const float*)d_in[o + 0];
    p.ioux_b[d] = (const float*)d_in[o + 1];
    p.iouh_w[d] = (const float*)d_in[o + 2];
    p.iouh_b[d] = (const float*)d_in[o + 3];
    p.fx_w[d]   = (const float*)d_in[o + 4];
    p.fx_b[d]   = (const float*)d_in[o + 5];
    p.fh_w[d]   = (const float*)d_in[o + 6];
    p.fh_b[d]   = (const float*)d_in[o + 7];
  }

  // workspace carve
  unsigned short* a16   = (unsigned short*)d_ws;        // 8,388,608
  unsigned short* w16x  = a16 + 8388608u;               // 524,288
  unsigned short* w16h  = w16x + 524288u;               // 524,288
  unsigned short* xproj = w16h + 524288u;               // 67,108,864
  float* bias4 = (float*)(xproj + 67108864u);           // 2048
  int*   lev_g   = (int*)(bias4 + 2048u);               // 65,536
  int*   csr_off = lev_g + 65536;                       // 128*260
  int*   csr_dat = csr_off + 33280;                     // 32,768
  int*   lvcnt   = csr_dat + 32768;                     // 2*NLEV
  int*   lvoff   = lvcnt + 2 * NLEV;                    // 2*(NLEV+1)
  int*   lvcur   = lvoff + 2 * (NLEV + 1);              // 2*NLEV
  unsigned* plist = (unsigned*)(lvcur + 2 * NLEV);      // 2*32768

  float* cells = (float*)d_out;                         // [256][128][512]
  float* hidd  = cells + 16777216u;

  prep_kernel<<<dim3(2048), dim3(256), 0, stream>>>(p, a16, w16x, w16h, bias4, lvcnt);
  levels_kernel<<<dim3(128), dim3(256), 0, stream>>>(parents, lev_g, csr_off, csr_dat, lvcnt);
  scan_kernel<<<dim3(1), dim3(128), 0, stream>>>(lvcnt, lvoff, lvcur);
  scatter_kernel<<<dim3(128, 2), dim3(256), 0, stream>>>(lev_g, lvcur, plist);
  xproj_gemm<<<dim3(2048, 16, 2), dim3(256), 0, stream>>>(a16, w16x, xproj);
  for (int l = 0; l < NLEV; ++l) {
    step_kernel<<<dim3(256, 1, 2), dim3(256), 0, stream>>>(l, w16h, bias4, xproj,
        lvoff, plist, csr_off, csr_dat, parents, cells, hidd);
  }
}

// Round 3
// 1300.474 us; speedup vs baseline: 3.0582x; 1.5005x over previous
//
#include <hip/hip_runtime.h>

#define LL 256
#define BB 128
#define NLEV 48

typedef float  floatx4 __attribute__((ext_vector_type(4)));
typedef short  short8  __attribute__((ext_vector_type(8)));

struct Params {
  const float* inputs;
  const float* ioux_w[2]; const float* ioux_b[2];
  const float* iouh_w[2]; const float* iouh_b[2];
  const float* fx_w[2];   const float* fx_b[2];
  const float* fh_w[2];   const float* fh_b[2];
};

__device__ __forceinline__ unsigned short f2bf(float f) {
  unsigned u = __float_as_uint(f);
  u += 0x7fffu + ((u >> 16) & 1u);
  return (unsigned short)(u >> 16);
}
__device__ __forceinline__ float bf2f(unsigned u) { return __uint_as_float(u << 16); }
__device__ __forceinline__ float sigm(float x) { return 1.0f / (1.0f + __expf(-x)); }
__device__ __forceinline__ float tanh_(float x) { return 1.0f - 2.0f / (1.0f + __expf(2.0f * x)); }

// ---------------------------------------------------------------------------
// prep: bf16 inputs; bf16 x-weights and h-weights in natural gate-planar rows
// cc = g*256+j (rows 0..767 = iou, 768..1023 = f); folded bias[d][1024].
// ---------------------------------------------------------------------------
__global__ __launch_bounds__(256) void prep_kernel(Params p,
    unsigned short* a16, unsigned short* w16x, unsigned short* w16h,
    float* bias, int* lvcnt) {
  size_t tid = (size_t)blockIdx.x * blockDim.x + threadIdx.x;
  size_t nth = (size_t)gridDim.x * blockDim.x;

  const float4* in4 = (const float4*)p.inputs;
  for (size_t i = tid; i < 2097152u; i += nth) {
    float4 v = in4[i];
    ((ushort4*)a16)[i] = make_ushort4(f2bf(v.x), f2bf(v.y), f2bf(v.z), f2bf(v.w));
  }
  for (size_t i = tid; i < 524288u; i += nth) {
    int d = (int)(i >> 18); int r = (int)(i & 262143);
    int cc = r >> 8; int k = r & 255;
    float sx = (cc < 768) ? p.ioux_w[d][cc * 256 + k] : p.fx_w[d][(cc - 768) * 256 + k];
    float sh = (cc < 768) ? p.iouh_w[d][cc * 256 + k] : p.fh_w[d][(cc - 768) * 256 + k];
    w16x[i] = f2bf(sx);
    w16h[i] = f2bf(sh);
  }
  for (size_t i = tid; i < 2048u; i += nth) {
    int d = (int)(i >> 10); int cc = (int)(i & 1023);
    bias[i] = (cc < 768) ? (p.ioux_b[d][cc] + p.iouh_b[d][cc])
                         : (p.fx_b[d][cc - 768] + p.fh_b[d][cc - 768]);
  }
  for (size_t i = tid; i < 2u * NLEV; i += nth) lvcnt[i] = 0;
}

// ---------------------------------------------------------------------------
// levels: per-b tree walks -> dt heights, td depths; children CSR; histograms.
// ---------------------------------------------------------------------------
__global__ __launch_bounds__(256) void levels_kernel(
    const int* __restrict__ parents, int* __restrict__ lev_g,
    int* __restrict__ csr_off, int* __restrict__ csr_dat, int* __restrict__ lvcnt) {
  __shared__ int parL[256], lvdt[256], lvtd[256];
  __shared__ int cmax[257], ccnt[257], coff[257], ccur[257];
  __shared__ int histd[NLEV], histt[NLEV];
  int b = blockIdx.x, t = threadIdx.x;

  parL[t] = parents[t * BB + b];
  for (int v = t; v < 257; v += 256) { cmax[v] = -1; ccnt[v] = 0; }
  if (t < NLEV) { histd[t] = 0; histt[t] = 0; }
  __syncthreads();

  if (t == 0) {
    lvtd[0] = 0;
    for (int i = 1; i < 256; ++i) lvtd[i] = lvtd[parL[i]] + 1;
  }
  if (t == 1) {
    for (int i = 255; i >= 1; --i) {
      int l = cmax[i] + 1;
      lvdt[i] = l;
      int p = parL[i];
      if (cmax[p] < l) cmax[p] = l;
    }
    lvdt[0] = cmax[0] + 1;
  }
  __syncthreads();

  int l1 = min(lvdt[t], NLEV - 1);
  int l2 = min(lvtd[t], NLEV - 1);
  atomicAdd(&histd[l1], 1);
  atomicAdd(&histt[l2], 1);
  if (t >= 1) atomicAdd(&ccnt[parL[t]], 1);
  lev_g[b * 256 + t] = l1;
  lev_g[32768 + b * 256 + t] = l2;
  __syncthreads();

  if (t == 0) {
    int s = 0;
    for (int i = 0; i < 257; ++i) { coff[i] = s; s += ccnt[i]; }
  }
  __syncthreads();
  for (int v = t; v < 257; v += 256) ccur[v] = coff[v];
  __syncthreads();
  if (t >= 1) {
    int pos = atomicAdd(&ccur[parL[t]], 1);
    csr_dat[b * 256 + pos] = t;
  }
  for (int v = t; v < 257; v += 256) csr_off[b * 260 + v] = coff[v];
  if (t < NLEV) {
    if (histd[t]) atomicAdd(&lvcnt[t], histd[t]);
    if (histt[t]) atomicAdd(&lvcnt[NLEV + t], histt[t]);
  }
}

__global__ __launch_bounds__(128) void scan_kernel(const int* __restrict__ lvcnt,
                                                   int* __restrict__ lvoff,
                                                   int* __restrict__ lvcur) {
  __shared__ int c[2 * NLEV], o[2 * (NLEV + 1)];
  int t = threadIdx.x;
  if (t < 2 * NLEV) c[t] = lvcnt[t];
  __syncthreads();
  if (t < 2) {
    int s = 0;
    for (int l = 0; l < NLEV; ++l) { o[t * (NLEV + 1) + l] = s; s += c[t * NLEV + l]; }
    o[t * (NLEV + 1) + NLEV] = s;
  }
  __syncthreads();
  if (t < 2 * (NLEV + 1)) lvoff[t] = o[t];
  if (t < 2 * NLEV) lvcur[t] = o[(t / NLEV) * (NLEV + 1) + (t % NLEV)];
}

__global__ __launch_bounds__(256) void scatter_kernel(const int* __restrict__ lev_g,
    int* __restrict__ lvcur, unsigned* __restrict__ plist) {
  __shared__ int hist[NLEV], base[NLEV], cnt2[NLEV];
  int b = blockIdx.x, d = blockIdx.y, t = threadIdx.x;
  if (t < NLEV) { hist[t] = 0; cnt2[t] = 0; }
  __syncthreads();
  int l = lev_g[d * 32768 + b * 256 + t];
  atomicAdd(&hist[l], 1);
  __syncthreads();
  if (t < NLEV && hist[t] > 0) base[t] = atomicAdd(&lvcur[d * NLEV + t], hist[t]);
  __syncthreads();
  int r = atomicAdd(&cnt2[l], 1);
  plist[d * 32768 + base[l] + r] = ((unsigned)b << 16) | (unsigned)t;
}

// ---------------------------------------------------------------------------
// xproj GEMM, tiled: 128x128 tile, BK=64, LDS-staged. Grid (256, 16).
// blockIdx.y: d = y>>3, cc0 = (y&7)*128. Out xp[d][m=node*128+b][cc] bf16.
// ---------------------------------------------------------------------------
__global__ __launch_bounds__(256) void xproj_gemm(
    const unsigned short* __restrict__ a16,
    const unsigned short* __restrict__ w16x,
    unsigned short* __restrict__ xp) {
  __shared__ unsigned short As[128 * 72], Bs[128 * 72];
  int t = threadIdx.x;
  int w = t >> 6, lane = t & 63, l16 = lane & 15, quad = lane >> 4;
  int m0 = blockIdx.x * 128;
  int d = blockIdx.y >> 3;
  int cc0 = (blockIdx.y & 7) * 128;
  const unsigned short* Bg = w16x + ((size_t)d * 1024 + cc0) * 256;
  int lr = t >> 3, seg = t & 7;

  floatx4 acc[4][4];
#pragma unroll
  for (int i = 0; i < 4; ++i)
#pragma unroll
    for (int j = 0; j < 4; ++j) acc[i][j] = (floatx4){0.f, 0.f, 0.f, 0.f};

  for (int ck = 0; ck < 4; ++ck) {
    int k0 = ck * 64;
#pragma unroll
    for (int it = 0; it < 4; ++it) {
      int row = it * 32 + lr;
      *(uint4*)&As[row * 72 + seg * 8] =
          *(const uint4*)(a16 + (size_t)(m0 + row) * 256 + k0 + seg * 8);
      *(uint4*)&Bs[row * 72 + seg * 8] =
          *(const uint4*)(Bg + (size_t)row * 256 + k0 + seg * 8);
    }
    __syncthreads();
#pragma unroll
    for (int kc = 0; kc < 2; ++kc) {
      int kg = kc * 4 + quad;
      short8 af[4], bf[4];
#pragma unroll
      for (int mf = 0; mf < 4; ++mf)
        af[mf] = *(const short8*)&As[((w & 1) * 64 + mf * 16 + l16) * 72 + kg * 8];
#pragma unroll
      for (int nf = 0; nf < 4; ++nf)
        bf[nf] = *(const short8*)&Bs[((w >> 1) * 64 + nf * 16 + l16) * 72 + kg * 8];
#pragma unroll
      for (int mf = 0; mf < 4; ++mf)
#pragma unroll
        for (int nf = 0; nf < 4; ++nf)
          acc[mf][nf] = __builtin_amdgcn_mfma_f32_16x16x32_bf16(af[mf], bf[nf], acc[mf][nf], 0, 0, 0);
    }
    __syncthreads();
  }
  unsigned short* out = xp + (size_t)d * 33554432u;
#pragma unroll
  for (int mf = 0; mf < 4; ++mf)
#pragma unroll
    for (int nf = 0; nf < 4; ++nf)
#pragma unroll
      for (int r = 0; r < 4; ++r) {
        int row = m0 + (w & 1) * 64 + mf * 16 + quad * 4 + r;
        int col = cc0 + (w >> 1) * 64 + nf * 16 + l16;
        out[(size_t)row * 1024 + col] = f2bf(acc[mf][nf][r]);
      }
}

// ---------------------------------------------------------------------------
// gather: per pair of level l, build bf16 A-row (dt: sum of children h;
// td: parent h). Grid (128, 1, 2), 256 thr (1 wave = 1 pair).
// ---------------------------------------------------------------------------
__global__ __launch_bounds__(256) void gather_kernel(int l,
    const int* __restrict__ lvoff, const unsigned* __restrict__ plist,
    const int* __restrict__ csr_off, const int* __restrict__ csr_dat,
    const int* __restrict__ parents, const float* __restrict__ hidd,
    unsigned short* __restrict__ A16ws) {
  int d = blockIdx.z;
  int i0 = lvoff[d * (NLEV + 1) + l];
  int i1 = lvoff[d * (NLEV + 1) + l + 1];
  int wv = threadIdx.x >> 6, lane = threadIdx.x & 63;
  for (int gi = i0 + blockIdx.x * 4 + wv; gi < i1; gi += 512) {
    unsigned pr = plist[d * 32768 + gi];
    int b = pr >> 16, node = pr & 0xffff;
    float sx = 0.f, sy = 0.f, sz = 0.f, sw = 0.f;
    if (d == 0) {
      int o0 = csr_off[b * 260 + node], o1 = csr_off[b * 260 + node + 1];
      for (int e = o0; e < o1; ++e) {
        int cn = csr_dat[b * 256 + e];
        float4 v = *(const float4*)(hidd + ((size_t)cn * BB + b) * 512 + lane * 4);
        sx += v.x; sy += v.y; sz += v.z; sw += v.w;
      }
    } else {
      int par = parents[node * BB + b];
      if (par != LL) {
        float4 v = *(const float4*)(hidd + ((size_t)par * BB + b) * 512 + 256 + lane * 4);
        sx = v.x; sy = v.y; sz = v.z; sw = v.w;
      }
    }
    *(ushort4*)&A16ws[(size_t)d * 8388608u + (size_t)gi * 256 + lane * 4] =
        make_ushort4(f2bf(sx), f2bf(sy), f2bf(sz), f2bf(sw));
  }
}

// ---------------------------------------------------------------------------
// level GEMM: M-tile 128 pairs x N-tile 128 (32 j x 4 gates), BK=64,
// LDS-staged, fused gating epilogue (sc re-gathered). Grid (32, 8, 2).
// ---------------------------------------------------------------------------
__global__ __launch_bounds__(256) void level_gemm(int l,
    const unsigned short* __restrict__ w16h, const float* __restrict__ bias,
    const unsigned short* __restrict__ xp,
    const int* __restrict__ lvoff, const unsigned* __restrict__ plist,
    const int* __restrict__ csr_off, const int* __restrict__ csr_dat,
    const int* __restrict__ parents, const unsigned short* __restrict__ A16ws,
    float* __restrict__ cells, float* __restrict__ hidd) {
  __shared__ unsigned short As[128 * 72], Bs[128 * 72];
  int d = blockIdx.z;
  int i0 = lvoff[d * (NLEV + 1) + l];
  int i1 = lvoff[d * (NLEV + 1) + l + 1];
  int np = i1 - i0;
  if (np <= 0) return;
  int ntiles = (np + 127) >> 7;

  int t = threadIdx.x;
  int w = t >> 6, lane = t & 63, l16 = lane & 15, quad = lane >> 4;
  int j0 = blockIdx.y * 32;
  const unsigned short* Bg = w16h + (size_t)d * 262144u;
  const unsigned short* Ag = A16ws + (size_t)d * 8388608u;
  int lr = t >> 3, seg = t & 7;

  for (int mt = blockIdx.x; mt < ntiles; mt += gridDim.x) {
    floatx4 acc[2][4][2];
#pragma unroll
    for (int mf = 0; mf < 2; ++mf)
#pragma unroll
      for (int g = 0; g < 4; ++g)
#pragma unroll
        for (int js = 0; js < 2; ++js) acc[mf][g][js] = (floatx4){0.f, 0.f, 0.f, 0.f};

    for (int ck = 0; ck < 4; ++ck) {
      int k0 = ck * 64;
#pragma unroll
      for (int it = 0; it < 4; ++it) {
        int row = it * 32 + lr;
        int gi = i0 + mt * 128 + row;
        uint4 av = make_uint4(0u, 0u, 0u, 0u);
        if (gi < i1) av = *(const uint4*)(Ag + (size_t)gi * 256 + k0 + seg * 8);
        *(uint4*)&As[row * 72 + seg * 8] = av;
        int cc = ((row >> 5) << 8) + j0 + (row & 31);
        *(uint4*)&Bs[row * 72 + seg * 8] =
            *(const uint4*)(Bg + (size_t)cc * 256 + k0 + seg * 8);
      }
      __syncthreads();
#pragma unroll
      for (int kc = 0; kc < 2; ++kc) {
        int kg = kc * 4 + quad;
        short8 af[2];
#pragma unroll
        for (int mf = 0; mf < 2; ++mf)
          af[mf] = *(const short8*)&As[(w * 32 + mf * 16 + l16) * 72 + kg * 8];
#pragma unroll
        for (int g = 0; g < 4; ++g)
#pragma unroll
          for (int js = 0; js < 2; ++js) {
            short8 bf = *(const short8*)&Bs[(g * 32 + js * 16 + l16) * 72 + kg * 8];
            acc[0][g][js] = __builtin_amdgcn_mfma_f32_16x16x32_bf16(af[0], bf, acc[0][g][js], 0, 0, 0);
            acc[1][g][js] = __builtin_amdgcn_mfma_f32_16x16x32_bf16(af[1], bf, acc[1][g][js], 0, 0, 0);
          }
      }
      __syncthreads();
    }

    // epilogue: fused bias + xproj + gating; sc re-gathered (uniform per row)
#pragma unroll
    for (int mf = 0; mf < 2; ++mf)
#pragma unroll
      for (int r = 0; r < 4; ++r) {
        int row = w * 32 + mf * 16 + quad * 4 + r;
        int gi = i0 + mt * 128 + row;
        if (gi >= i1) continue;
        unsigned pr = plist[d * 32768 + gi];
        int b = pr >> 16, node = pr & 0xffff;
        float sc0 = 0.f, sc1 = 0.f;
        if (d == 0) {
          int o0 = csr_off[b * 260 + node], o1 = csr_off[b * 260 + node + 1];
          for (int e = o0; e < o1; ++e) {
            int cn = csr_dat[b * 256 + e];
            const float* cbase = cells + ((size_t)cn * BB + b) * 512;
            sc0 += cbase[j0 + l16];
            sc1 += cbase[j0 + 16 + l16];
          }
        } else {
          int par = parents[node * BB + b];
          if (par != LL) {
            const float* cbase = cells + ((size_t)par * BB + b) * 512 + 256;
            sc0 = cbase[j0 + l16];
            sc1 = cbase[j0 + 16 + l16];
          }
        }
        const unsigned short* xrow = xp + (size_t)d * 33554432u + ((size_t)node * BB + b) * 1024;
        const float* brow = bias + d * 1024;
#pragma unroll
        for (int js = 0; js < 2; ++js) {
          int j = j0 + js * 16 + l16;
          float sc = js ? sc1 : sc0;
          float pi = acc[mf][0][js][r] + brow[j]       + bf2f(xrow[j]);
          float po = acc[mf][1][js][r] + brow[256 + j] + bf2f(xrow[256 + j]);
          float pu = acc[mf][2][js][r] + brow[512 + j] + bf2f(xrow[512 + j]);
          float pf = acc[mf][3][js][r] + brow[768 + j] + bf2f(xrow[768 + j]);
          float gi_ = sigm(pi), go = sigm(po), gu = tanh_(pu), gf = sigm(pf);
          float c = gi_ * gu + gf * sc;
          float h = go * tanh_(c);
          size_t ob = ((size_t)node * BB + b) * 512 + (d << 8) + j;
          cells[ob] = c;
          hidd[ob] = h;
        }
      }
  }
}

// ---------------------------------------------------------------------------
extern "C" void kernel_launch(void* const* d_in, const int* in_sizes, int n_in,
                              void* d_out, int out_size, void* d_ws, size_t ws_size,
                              hipStream_t stream) {
  Params p;
  p.inputs = (const float*)d_in[0];
  const int* parents = (const int*)d_in[2];
  for (int d = 0; d < 2; ++d) {
    int o = 3 + d * 8;
    p.ioux_w[d] = (const float*)d_in[o + 0];
    p.ioux_b[d] = (const float*)d_in[o + 1];
    p.iouh_w[d] = (const float*)d_in[o + 2];
    p.iouh_b[d] = (const float*)d_in[o + 3];
    p.fx_w[d]   = (const float*)d_in[o + 4];
    p.fx_b[d]   = (const float*)d_in[o + 5];
    p.fh_w[d]   = (const float*)d_in[o + 6];
    p.fh_b[d]   = (const float*)d_in[o + 7];
  }

  unsigned short* a16   = (unsigned short*)d_ws;        // 8,388,608 u16
  unsigned short* w16x  = a16 + 8388608u;               // 524,288
  unsigned short* w16h  = w16x + 524288u;               // 524,288
  unsigned short* xp    = w16h + 524288u;               // 67,108,864
  unsigned short* A16ws = xp + 67108864u;               // 16,777,216
  float* bias = (float*)(A16ws + 16777216u);            // 2048 f32
  int*   lev_g   = (int*)(bias + 2048u);                // 65,536
  int*   csr_off = lev_g + 65536;                       // 33,280
  int*   csr_dat = csr_off + 33280;                     // 32,768
  int*   lvcnt   = csr_dat + 32768;                     // 96
  int*   lvoff   = lvcnt + 2 * NLEV;                    // 98
  int*   lvcur   = lvoff + 2 * (NLEV + 1);              // 96
  unsigned* plist = (unsigned*)(lvcur + 2 * NLEV);      // 65,536

  float* cells = (float*)d_out;                         // [256][128][512]
  float* hidd  = cells + 16777216u;

  prep_kernel<<<dim3(1024), dim3(256), 0, stream>>>(p, a16, w16x, w16h, bias, lvcnt);
  levels_kernel<<<dim3(128), dim3(256), 0, stream>>>(parents, lev_g, csr_off, csr_dat, lvcnt);
  scan_kernel<<<dim3(1), dim3(128), 0, stream>>>(lvcnt, lvoff, lvcur);
  scatter_kernel<<<dim3(128, 2), dim3(256), 0, stream>>>(lev_g, lvcur, plist);
  xproj_gemm<<<dim3(256, 16), dim3(256), 0, stream>>>(a16, w16x, xp);
  for (int l = 0; l < NLEV; ++l) {
    gather_kernel<<<dim3(128, 1, 2), dim3(256), 0, stream>>>(l, lvoff, plist,
        csr_off, csr_dat, parents, hidd, A16ws);
    level_gemm<<<dim3(32, 8, 2), dim3(256), 0, stream>>>(l, w16h, bias, xp,
        lvoff, plist, csr_off, csr_dat, parents, A16ws, cells, hidd);
  }
}